// Round 7
// baseline (120.545 us; speedup 1.0000x reference)
//
#include <hip/hip_runtime.h>

// Submanifold sparse conv — 3 dispatches.
//   1. hipMemsetAsync grid+bitmap to 0
//   2. build_grid: atomicMax(grid[key], n-i) + atomicOr(bitmap bit)
//   3. conv: block = 32 points, NTHR = 256 (4 waves). R6 post-mortem: waves
//      within a block are barrier-locked into the same phase -> they stall
//      together; only ~2.3 independent blocks/CU hid latency (LDS 37.4KB
//      capped 4 blocks/CU). R7 lever: shrink the barrier-group. PTS 64->32
//      cuts LDS to ~21KB -> 7 blocks/CU = 7 INDEPENDENT phase chains
//      interleaving per CU (87% occupancy). Structure per block unchanged:
//        P0  stage pos -> LDS
//        P1a bitmap-only probes (L2-resident 275 KB) -> per-offset lists
//        scan wave0 prefix-sums counts -> flat row segments (centers f=pl,
//             neighbors from f=32)
//        P1b resolve grid lookups in one parallel batch -> s_jidx[f] = j
//        P1c DMA-gather: ONE global_load_lds per 8 rows (lane l reads 16B of
//             row l>>3 from feat[j]; HW writes LDS base+lane*16), ~9 instrs,
//             ONE vmcnt(0) drain (hipcc can't sink async DMA -> MLP survives)
//        P3a center drain: row f=pl from LDS (same-addr broadcast), plain-
//             store init of s_acc
//        P3b neighbor drain: HALF-WAVE h owns offsets o=h,h+8,... (keeps the
//             per-wave serial weight-load chain at ~3.3 offsets despite half
//             the waves); W[o] column in 32 VGPRs amortized per (block,offset);
//             rows from LDS; ds_add_f32 into s_acc
//        P4  coalesced write-out

#define GRID_B 130
#define GRID_CELLS 2197000      // 130^3
#define BM_WORDS 68704          // ceil(130^3/32)=68657, padded for w+1 reads
#define C 32
#define NTHR 256
#define PTS 32                  // points per block
#define CAP 14                  // per-offset list cap (Binom(32,0.048), +9sigma)
#define ROWS_CAP 112            // flat row cap (mean 72, sigma 6.2, +6.5sigma)

__global__ void build_grid_kernel(const int* __restrict__ pos,
                                  int* __restrict__ grid,
                                  unsigned int* __restrict__ bm, int n) {
    int i = blockIdx.x * blockDim.x + threadIdx.x;
    if (i >= n) return;
    int x = pos[3 * i + 0] + 1;
    int y = pos[3 * i + 1] + 1;
    int z = pos[3 * i + 2] + 1;
    int key = (x * GRID_B + y) * GRID_B + z;
    atomicMax(&grid[key], n - i);
    atomicOr(&bm[key >> 5], 1u << (key & 31));
}

__global__ __launch_bounds__(NTHR)
void conv_kernel(const float* __restrict__ feat,
                 const int* __restrict__ pos,
                 const float* __restrict__ w,
                 const int* __restrict__ grid,
                 const unsigned int* __restrict__ bm,
                 float* __restrict__ out, int n) {
    __shared__ int   s_cnt[27];
    __shared__ int   s_seg[27];           // flat row segment start per offset
    __shared__ int   s_total;             // total gathered rows (incl 32 centers)
    __shared__ int   s_list[27][CAP];     // (pl<<22)|key
    __shared__ int   s_rep[PTS];          // center key
    __shared__ int   s_jidx[ROWS_CAP];    // resolved feature row index per flat slot
    __shared__ int   s_pos[PTS * 3];
    __shared__ __align__(16) float s_rows[ROWS_CAP][C]; // 14 KB DMA-gathered rows
    __shared__ __align__(16) float s_acc[PTS][C];       // 4 KB accumulator tile

    const int tid = threadIdx.x;
    const int pt_base = blockIdx.x * PTS;

    if (tid < 27) s_cnt[tid] = 0;
    // ---- P0: stage positions (coalesced) ----
    if (tid < PTS * 3) {
        int g = pt_base * 3 + tid;
        if (g < n * 3) s_pos[tid] = pos[g];
    }
    __syncthreads();

    // ---- P1a: 32 pts x 9 (dx,dy) columns; bitmap gives the z-triple ----
    for (int t = tid; t < PTS * 9; t += NTHR) {
        int pl = t / 9;
        int xy = t - pl * 9;
        if (pt_base + pl < n) {
            int dx = xy / 3;
            int dy = xy - dx * 3;
            int x0 = s_pos[pl * 3 + 0] + dx;
            int y0 = s_pos[pl * 3 + 1] + dy;
            int k0 = (x0 * GRID_B + y0) * GRID_B + s_pos[pl * 3 + 2];   // z-1 key
            unsigned int w0 = bm[(k0 >> 5)];
            unsigned int w1 = bm[(k0 >> 5) + 1];
            unsigned int bits =
                (unsigned int)((((unsigned long long)w1 << 32) | w0) >> (k0 & 31)) & 7u;
            int obase = xy * 3;
            if (xy == 4) {
                s_rep[pl] = k0 + 1;      // center key; resolved in P1b
                bits &= 5u;
            }
            while (bits) {
                int oz = __ffs(bits) - 1;
                bits &= bits - 1;
                int slot = atomicAdd(&s_cnt[obase + oz], 1);
                if (slot < CAP) s_list[obase + oz][slot] = (pl << 22) | (k0 + oz);
            }
        }
    }
    __syncthreads();

    // ---- scan: wave0 prefix-sums counts into flat segments ----
    if (tid < 64) {
        int o = tid;
        int c = (o < 27 && o != 13) ? min(s_cnt[o], CAP) : 0;
        int x = c;
        #pragma unroll
        for (int d = 1; d < 32; d <<= 1) {
            int y = __shfl_up(x, d, 64);
            if (tid >= d) x += y;
        }
        if (o < 27) s_seg[o] = PTS + x - c;   // exclusive start, centers occupy [0,PTS)
        if (o == 26) s_total = PTS + x;
    }
    __syncthreads();

    // ---- P1b: resolve all grid lookups in one parallel batch -> s_jidx ----
    for (int t = tid; t < 27 * CAP + PTS; t += NTHR) {
        if (t < 27 * CAP) {
            int o = t / CAP;
            int slot = t - o * CAP;
            if (o != 13 && slot < min(s_cnt[o], CAP)) {
                int f = s_seg[o] + slot;
                if (f < ROWS_CAP)
                    s_jidx[f] = n - grid[s_list[o][slot] & 0x3FFFFF];
            }
        } else {
            int pl = t - 27 * CAP;
            s_jidx[pl] = (pt_base + pl < n) ? (n - grid[s_rep[pl]]) : 0;
        }
    }
    __syncthreads();

    // ---- P1c: DMA-gather all rows into s_rows ----
    {
        int totc = min(s_total, ROWS_CAP);
        int lane = tid & 63, wv = tid >> 6;   // 4 waves
        int nI = (totc + 7) >> 3;             // 8 rows per instruction
        for (int i = wv; i < nI; i += 4) {
            int f = (i << 3) + (lane >> 3);
            int j = s_jidx[min(f, totc - 1)];         // clamped dup for tail lanes
            const float* g = feat + (size_t)j * C + ((lane & 7) << 2);
            __builtin_amdgcn_global_load_lds(
                (const __attribute__((address_space(1))) unsigned int*)g,
                (__attribute__((address_space(3))) unsigned int*)(&s_rows[i << 3][0]),
                16, 0, 0);                    // HW: LDS base + lane*16
        }
    }
    asm volatile("s_waitcnt vmcnt(0)" ::: "memory");
    __syncthreads();

    // ---- P3a: center drain; row f=pl; plain-store init of s_acc ----
    {
        const int hw8 = tid >> 5;             // half-wave 0..7
        const int cout = tid & 31;
        const int cnt13 = min(PTS, n - pt_base);
        float wreg[32];
        #pragma unroll
        for (int c = 0; c < 32; ++c) wreg[c] = w[13 * 1024 + c * 32 + cout];
        for (int e = hw8; e < cnt13; e += 8) {
            const float4* R = (const float4*)(&s_rows[e][0]);   // broadcast reads
            float acc = 0.0f;
            #pragma unroll
            for (int k = 0; k < 8; ++k) {
                float4 rv = R[k];
                acc = fmaf(rv.x, wreg[4 * k + 0], acc);
                acc = fmaf(rv.y, wreg[4 * k + 1], acc);
                acc = fmaf(rv.z, wreg[4 * k + 2], acc);
                acc = fmaf(rv.w, wreg[4 * k + 3], acc);
            }
            s_acc[e][cout] = acc;
        }
    }
    __syncthreads();

    // ---- P3b: neighbor drain; half-wave h owns offsets o=h,h+8,... ----
    {
        const int hw8 = tid >> 5;             // half-wave 0..7
        const int cout = tid & 31;
        for (int o = hw8; o < 27; o += 8) {
            if (o == 13) continue;
            int cnt = min(s_cnt[o], CAP);
            if (cnt == 0) continue;
            int seg = s_seg[o];
            float wreg[32];
            #pragma unroll
            for (int c = 0; c < 32; ++c) wreg[c] = w[o * 1024 + c * 32 + cout];
            for (int e = 0; e < cnt; ++e) {
                int f = seg + e;
                if (f >= ROWS_CAP) break;
                int pl = ((unsigned int)s_list[o][e]) >> 22;
                const float4* R = (const float4*)(&s_rows[f][0]);
                float acc = 0.0f;
                #pragma unroll
                for (int k = 0; k < 8; ++k) {
                    float4 rv = R[k];
                    acc = fmaf(rv.x, wreg[4 * k + 0], acc);
                    acc = fmaf(rv.y, wreg[4 * k + 1], acc);
                    acc = fmaf(rv.z, wreg[4 * k + 2], acc);
                    acc = fmaf(rv.w, wreg[4 * k + 3], acc);
                }
                atomicAdd(&s_acc[pl][cout], acc);     // ds_add_f32
            }
        }
    }
    __syncthreads();

    // ---- P4: coalesced write-out (block owns its 32 points exclusively) ----
    {
        const int base = pt_base * C;
        const int lim = n * C - base;
        for (int u = tid; u < PTS * C && u < lim; u += NTHR)
            out[base + u] = s_acc[u >> 5][u & 31];
    }
}

extern "C" void kernel_launch(void* const* d_in, const int* in_sizes, int n_in,
                              void* d_out, int out_size, void* d_ws, size_t ws_size,
                              hipStream_t stream) {
    const float* features = (const float*)d_in[0];
    const int*   positions = (const int*)d_in[1];
    const float* weight = (const float*)d_in[2];
    float* out = (float*)d_out;
    const int n = in_sizes[0] / C;       // 100000

    int* grid = (int*)d_ws;
    unsigned int* bm = (unsigned int*)(grid + GRID_CELLS);
    hipMemsetAsync(d_ws, 0, (size_t)(GRID_CELLS + BM_WORDS) * sizeof(int), stream);

    build_grid_kernel<<<(n + 255) / 256, 256, 0, stream>>>(positions, grid, bm, n);

    conv_kernel<<<(n + PTS - 1) / PTS, NTHR, 0, stream>>>(features, positions, weight,
                                                          grid, bm, out, n);
}